// Round 1
// baseline (292.910 us; speedup 1.0000x reference)
//
#include <hip/hip_runtime.h>
#include <hip/hip_bf16.h>

typedef float f32x4 __attribute__((ext_vector_type(4)));

#define FP8_MAX_F 448.0f

__device__ __forceinline__ float wave_max(float m) {
#pragma unroll
    for (int off = 32; off > 0; off >>= 1)
        m = fmaxf(m, __shfl_xor(m, off));
    return m;
}

// ---------------- amax reduction (abs-max -> atomicMax on uint bits) ----------------
__global__ void amax_kernel(const float* __restrict__ x, long n, unsigned* __restrict__ out) {
    const long stride = (long)gridDim.x * blockDim.x * 4;
    long i = ((long)blockIdx.x * blockDim.x + threadIdx.x) * 4;
    float m = 0.0f;
    for (; i < n; i += stride) {
        f32x4 v = *(const f32x4*)(x + i);
        m = fmaxf(fmaxf(fabsf(v.x), fabsf(v.y)),
                  fmaxf(fmaxf(fabsf(v.z), fabsf(v.w)), m));
    }
    m = wave_max(m);
    if ((threadIdx.x & 63) == 0)
        atomicMax(out, __float_as_uint(m));
}

// ---------------- quantize f32 -> fp8 e4m3fn (RNE, matches jnp clip+astype) ----------------
__global__ void quant_kernel(const float* __restrict__ x, long n4,
                             const unsigned* __restrict__ amax_bits,
                             unsigned* __restrict__ q) {
    const float a = __uint_as_float(*amax_bits);
    const float scale = fminf(FP8_MAX_F / fmaxf(a, 1e-12f), FP8_MAX_F);
    const long stride = (long)gridDim.x * blockDim.x;
    for (long i = (long)blockIdx.x * blockDim.x + threadIdx.x; i < n4; i += stride) {
        f32x4 v = *(const f32x4*)(x + i * 4);
        float x0 = fminf(fmaxf(v.x * scale, -FP8_MAX_F), FP8_MAX_F);
        float x1 = fminf(fmaxf(v.y * scale, -FP8_MAX_F), FP8_MAX_F);
        float x2 = fminf(fmaxf(v.z * scale, -FP8_MAX_F), FP8_MAX_F);
        float x3 = fminf(fmaxf(v.w * scale, -FP8_MAX_F), FP8_MAX_F);
        int r = __builtin_amdgcn_cvt_pk_fp8_f32(x0, x1, 0, false);
        r = __builtin_amdgcn_cvt_pk_fp8_f32(x2, x3, r, true);
        q[i] = (unsigned)r;
    }
}

// ---------------- fp8 GEMM: out[M,N] = dequant(Xq[M,K] @ Wq[N,K]^T) + bias ----------------
// m97 structure: 128x128 tile, BK=64, 4 waves (2x2), each wave 4x4 frags of 16x16x32.
__global__ __launch_bounds__(256) void gemm_fp8_kernel(
    const unsigned char* __restrict__ Xq,   // [M][K] fp8
    const unsigned char* __restrict__ Wq,   // [N][K] fp8
    const float* __restrict__ bias,         // [N]
    const unsigned* __restrict__ amax_bits, // [0]=x amax, [1]=w amax
    float* __restrict__ out,                // [M][N] f32 (bf16-rounded values)
    int M, int N, int K)
{
    __shared__ unsigned char lA[128 * 64];
    __shared__ unsigned char lB[128 * 64];

    const int tid  = threadIdx.x;
    const int lane = tid & 63;
    const int wave = tid >> 6;
    const int wm = wave >> 1;   // 0..1
    const int wn = wave & 1;    // 0..1

    const long row0 = (long)blockIdx.x * 128;
    const int  col0 = blockIdx.y * 128;

    const int l15 = lane & 15;
    const int lhi = lane >> 4;

    f32x4 acc[4][4] = {};

    for (int k0 = 0; k0 < K; k0 += 64) {
        // ---- stage A,B tiles: 8KB each, per wave: 2 chunks of 1KB (64 lanes x 16B) ----
#pragma unroll
        for (int it = 0; it < 2; ++it) {
            const int chunk = wave + it * 4;        // 0..7
            const int o = chunk * 1024 + lane * 16; // byte offset in [128][64] tile
            const int r = o >> 6;                   // row
            const int c = o & 63;                   // col within BK
            __builtin_amdgcn_global_load_lds(
                (const __attribute__((address_space(1))) void*)(Xq + (row0 + r) * K + k0 + c),
                (__attribute__((address_space(3))) void*)(lA + chunk * 1024), 16, 0, 0);
            __builtin_amdgcn_global_load_lds(
                (const __attribute__((address_space(1))) void*)(Wq + (long)(col0 + r) * K + k0 + c),
                (__attribute__((address_space(3))) void*)(lB + chunk * 1024), 16, 0, 0);
        }
        __syncthreads();

        // ---- compute: 2 k-steps of 32, 4x4 frags ----
#pragma unroll
        for (int ks = 0; ks < 2; ++ks) {
            long a[4], b[4];
#pragma unroll
            for (int m = 0; m < 4; ++m)
                a[m] = *(const long*)(lA + (wm * 64 + m * 16 + l15) * 64 + ks * 32 + lhi * 8);
#pragma unroll
            for (int n = 0; n < 4; ++n)
                b[n] = *(const long*)(lB + (wn * 64 + n * 16 + l15) * 64 + ks * 32 + lhi * 8);
#pragma unroll
            for (int m = 0; m < 4; ++m)
#pragma unroll
                for (int n = 0; n < 4; ++n)
                    acc[m][n] = __builtin_amdgcn_mfma_f32_16x16x32_fp8_fp8(a[m], b[n], acc[m][n], 0, 0, 0);
        }
        __syncthreads();
    }

    // ---- epilogue: dequant scale, bias, bf16 round, f32 store ----
    const float ax = __uint_as_float(amax_bits[0]);
    const float aw = __uint_as_float(amax_bits[1]);
    const float sx = fminf(FP8_MAX_F / fmaxf(ax, 1e-12f), FP8_MAX_F);
    const float sw = fminf(FP8_MAX_F / fmaxf(aw, 1e-12f), FP8_MAX_F);
    const float s  = (1.0f / sx) * (1.0f / sw);   // x_scale * w_scale, f32 each step

#pragma unroll
    for (int n = 0; n < 4; ++n) {
        const int col = col0 + wn * 64 + n * 16 + l15;
        const float bv = bias[col];
#pragma unroll
        for (int m = 0; m < 4; ++m) {
#pragma unroll
            for (int r = 0; r < 4; ++r) {
                const long row = row0 + wm * 64 + m * 16 + lhi * 4 + r;
                float t = acc[m][n][r] * s;   // separate mul...
                t = t + bv;                   // ...then add (match jnp op order)
                out[row * N + col] = __bfloat162float(__float2bfloat16(t));
            }
        }
    }
}

extern "C" void kernel_launch(void* const* d_in, const int* in_sizes, int n_in,
                              void* d_out, int out_size, void* d_ws, size_t ws_size,
                              hipStream_t stream) {
    const float* input  = (const float*)d_in[0];
    const float* weight = (const float*)d_in[1];
    const float* bias   = (const float*)d_in[2];
    float* out = (float*)d_out;

    const int K = 1024;                       // weight [N,K] = [1024,1024]
    const int N = in_sizes[2];                // 1024 (bias length)
    const long nX = in_sizes[0];              // 33554432
    const int M = (int)(nX / K);              // 32768

    unsigned char* ws = (unsigned char*)d_ws;
    unsigned* amax = (unsigned*)ws;           // [0]=x amax bits, [1]=w amax bits
    unsigned char* Xq = ws + 256;
    unsigned char* Wq = ws + 256 + (size_t)M * K;

    // zero the amax slots (ws is poisoned; must re-zero every call)
    hipMemsetAsync(d_ws, 0, 16, stream);

    amax_kernel<<<2048, 256, 0, stream>>>(input, nX, amax + 0);
    amax_kernel<<<256, 256, 0, stream>>>(weight, (long)N * K, amax + 1);

    quant_kernel<<<2048, 256, 0, stream>>>(input, nX / 4, amax + 0, (unsigned*)Xq);
    quant_kernel<<<256, 256, 0, stream>>>(weight, (long)N * K / 4, amax + 1, (unsigned*)Wq);

    dim3 grid(M / 128, N / 128);
    gemm_fp8_kernel<<<grid, dim3(256), 0, stream>>>(Xq, Wq, bias, amax, out, M, N, K);
}

// Round 2
// 233.938 us; speedup vs baseline: 1.2521x; 1.2521x over previous
//
#include <hip/hip_runtime.h>
#include <hip/hip_bf16.h>

typedef float f32x4 __attribute__((ext_vector_type(4)));

#define FP8_MAX_F 448.0f

__device__ __forceinline__ float wave_max(float m) {
#pragma unroll
    for (int off = 32; off > 0; off >>= 1)
        m = fmaxf(m, __shfl_xor(m, off));
    return m;
}

// ---------------- fused amax: input (blocks < GA) + weight (rest) ----------------
__global__ void amax2_kernel(const float* __restrict__ x, long nx,
                             const float* __restrict__ w, long nw,
                             unsigned* __restrict__ ox, unsigned* __restrict__ ow,
                             int ga) {
    const float* src; long n; unsigned* dst; int bid, blocks;
    if ((int)blockIdx.x < ga) { src = x; n = nx; dst = ox; bid = blockIdx.x; blocks = ga; }
    else { src = w; n = nw; dst = ow; bid = blockIdx.x - ga; blocks = gridDim.x - ga; }

    const long stride = (long)blocks * blockDim.x * 16;
    long i = ((long)bid * blockDim.x + threadIdx.x) * 16;
    float m = 0.0f;
    for (; i < n; i += stride) {
        f32x4 v0 = *(const f32x4*)(src + i);
        f32x4 v1 = *(const f32x4*)(src + i + 4);
        f32x4 v2 = *(const f32x4*)(src + i + 8);
        f32x4 v3 = *(const f32x4*)(src + i + 12);
        float m0 = fmaxf(fmaxf(fabsf(v0.x), fabsf(v0.y)), fmaxf(fabsf(v0.z), fabsf(v0.w)));
        float m1 = fmaxf(fmaxf(fabsf(v1.x), fabsf(v1.y)), fmaxf(fabsf(v1.z), fabsf(v1.w)));
        float m2 = fmaxf(fmaxf(fabsf(v2.x), fabsf(v2.y)), fmaxf(fabsf(v2.z), fabsf(v2.w)));
        float m3 = fmaxf(fmaxf(fabsf(v3.x), fabsf(v3.y)), fmaxf(fabsf(v3.z), fabsf(v3.w)));
        m = fmaxf(m, fmaxf(fmaxf(m0, m1), fmaxf(m2, m3)));
    }
    m = wave_max(m);
    if ((threadIdx.x & 63) == 0)
        atomicMax(dst, __float_as_uint(m));
}

// ---------------- fused quantize (8 floats/thread/iter -> uint2) ----------------
__global__ void quant2_kernel(const float* __restrict__ x, long nx8,
                              const float* __restrict__ w, long nw8,
                              const unsigned* __restrict__ amax_bits,
                              unsigned* __restrict__ qx, unsigned* __restrict__ qw,
                              int ga) {
    const float* src; long n8; unsigned* q; int bid, blocks; float a;
    if ((int)blockIdx.x < ga) { src = x; n8 = nx8; q = qx; bid = blockIdx.x; blocks = ga;
                                a = __uint_as_float(amax_bits[0]); }
    else { src = w; n8 = nw8; q = qw; bid = blockIdx.x - ga; blocks = gridDim.x - ga;
           a = __uint_as_float(amax_bits[1]); }
    const float scale = fminf(FP8_MAX_F / fmaxf(a, 1e-12f), FP8_MAX_F);

    const long stride = (long)blocks * blockDim.x;
    for (long i = (long)bid * blockDim.x + threadIdx.x; i < n8; i += stride) {
        f32x4 v0 = *(const f32x4*)(src + i * 8);
        f32x4 v1 = *(const f32x4*)(src + i * 8 + 4);
        float c0 = fminf(fmaxf(v0.x * scale, -FP8_MAX_F), FP8_MAX_F);
        float c1 = fminf(fmaxf(v0.y * scale, -FP8_MAX_F), FP8_MAX_F);
        float c2 = fminf(fmaxf(v0.z * scale, -FP8_MAX_F), FP8_MAX_F);
        float c3 = fminf(fmaxf(v0.w * scale, -FP8_MAX_F), FP8_MAX_F);
        float c4 = fminf(fmaxf(v1.x * scale, -FP8_MAX_F), FP8_MAX_F);
        float c5 = fminf(fmaxf(v1.y * scale, -FP8_MAX_F), FP8_MAX_F);
        float c6 = fminf(fmaxf(v1.z * scale, -FP8_MAX_F), FP8_MAX_F);
        float c7 = fminf(fmaxf(v1.w * scale, -FP8_MAX_F), FP8_MAX_F);
        int r0 = __builtin_amdgcn_cvt_pk_fp8_f32(c0, c1, 0, false);
        r0 = __builtin_amdgcn_cvt_pk_fp8_f32(c2, c3, r0, true);
        int r1 = __builtin_amdgcn_cvt_pk_fp8_f32(c4, c5, 0, false);
        r1 = __builtin_amdgcn_cvt_pk_fp8_f32(c6, c7, r1, true);
        uint2 rr; rr.x = (unsigned)r0; rr.y = (unsigned)r1;
        *(uint2*)(q + i * 2) = rr;
    }
}

// ---------------- fp8 GEMM, 256x256 tile, BK=64, 8-phase pipelined ----------------
// LDS layout per slot: [c = kbyte/16][256 rows][16B], row swizzled r' = r ^ ((c&3)<<1).
// Stage is linear (global_load_lds); the inverse swizzle is applied to the global src addr.
__global__ __launch_bounds__(512, 2) void gemm_fp8_kernel(
    const unsigned char* __restrict__ Xq,   // [M][K] fp8
    const unsigned char* __restrict__ Wq,   // [N][K] fp8
    const float* __restrict__ bias,         // [N]
    const unsigned* __restrict__ amax_bits, // [0]=x amax, [1]=w amax
    float* __restrict__ out,                // [M][N] f32 (bf16-rounded values)
    int M, int N, int K, int nbn)
{
    __shared__ unsigned char ldsA[2][16384];
    __shared__ unsigned char ldsB[2][16384];

    const int tid  = threadIdx.x;
    const int lane = tid & 63;
    const int wave = tid >> 6;
    const int wm128 = (wave >> 2) * 128;  // 2 M-halves
    const int wn64  = (wave & 3) * 64;    // 4 N-quarters

    const int l15 = lane & 15;
    const int lhi = lane >> 4;            // 0..3
    const int h   = lhi >> 1;             // 0..1 (chunk half within 32-K)
    const int lo8 = (lhi & 1) * 8;

    // XCD-aware swizzle (nwg % 8 == 0), bn-fastest for A-panel L2 reuse
    const int cpx = gridDim.x >> 3;
    const int wg  = ((int)blockIdx.x & 7) * cpx + ((int)blockIdx.x >> 3);
    const int bn = wg % nbn;
    const int bm = wg / nbn;
    const int rowStart = bm << 8;
    const int colStart = bn << 8;

    // per-ks read-addressing constants (c = ks*2 + h, swz = (c&3)<<1)
    const int cb0  = (0 * 2 + h) * 4096 + lo8;
    const int cb1  = (1 * 2 + h) * 4096 + lo8;
    const int lsw0 = l15 ^ (2 * h);
    const int lsw1 = l15 ^ (4 + 2 * h);

    // staging source offsets (inverse swizzle on global row)
    const int c0  = tid >> 8;       // 0/1
    const int rr_ = tid & 255;
    size_t aoffs0, aoffs1, boffs0, boffs1;
    {
        int ca = c0;           int ra = rr_ ^ ((ca & 3) << 1);
        int cb_ = 2 + c0;      int rb = rr_ ^ ((cb_ & 3) << 1);
        aoffs0 = (size_t)(rowStart + ra) * K + ca * 16;
        aoffs1 = (size_t)(rowStart + rb) * K + cb_ * 16;
        boffs0 = (size_t)(colStart + ra) * K + ca * 16;
        boffs1 = (size_t)(colStart + rb) * K + cb_ * 16;
    }
    const int tid16 = tid * 16;

    f32x4 acc[8][4] = {};

#define STAGE(t, slot)                                                                          \
    do {                                                                                        \
        const size_t kk_ = (size_t)(t) * 64;                                                    \
        __builtin_amdgcn_global_load_lds(                                                       \
            (const __attribute__((address_space(1))) void*)(Xq + aoffs0 + kk_),                 \
            (__attribute__((address_space(3))) void*)(&ldsA[slot][tid16]), 16, 0, 0);           \
        __builtin_amdgcn_global_load_lds(                                                       \
            (const __attribute__((address_space(1))) void*)(Xq + aoffs1 + kk_),                 \
            (__attribute__((address_space(3))) void*)(&ldsA[slot][8192 + tid16]), 16, 0, 0);    \
        __builtin_amdgcn_global_load_lds(                                                       \
            (const __attribute__((address_space(1))) void*)(Wq + boffs0 + kk_),                 \
            (__attribute__((address_space(3))) void*)(&ldsB[slot][tid16]), 16, 0, 0);           \
        __builtin_amdgcn_global_load_lds(                                                       \
            (const __attribute__((address_space(1))) void*)(Wq + boffs1 + kk_),                 \
            (__attribute__((address_space(3))) void*)(&ldsB[slot][8192 + tid16]), 16, 0, 0);    \
    } while (0)

#define GPHASE(slot, ks, mh, VMW, STG)                                                          \
    do {                                                                                        \
        if (VMW) asm volatile("s_waitcnt vmcnt(0)" ::: "memory");                               \
        __builtin_amdgcn_s_barrier();                                                           \
        __builtin_amdgcn_sched_barrier(0);                                                      \
        const unsigned char* pA_ = &ldsA[slot][cb##ks + ((wm128 + (mh)*64 + lsw##ks) << 4)];    \
        const unsigned char* pB_ = &ldsB[slot][cb##ks + ((wn64 + lsw##ks) << 4)];               \
        long a_[4], b_[4];                                                                      \
        _Pragma("unroll")                                                                       \
        for (int q_ = 0; q_ < 4; ++q_) {                                                        \
            a_[q_] = *(const long*)(pA_ + q_ * 256);                                            \
            b_[q_] = *(const long*)(pB_ + q_ * 256);                                            \
        }                                                                                       \
        STG;                                                                                    \
        __builtin_amdgcn_s_setprio(1);                                                          \
        _Pragma("unroll")                                                                       \
        for (int mi_ = 0; mi_ < 4; ++mi_)                                                       \
            _Pragma("unroll")                                                                   \
            for (int ni_ = 0; ni_ < 4; ++ni_)                                                   \
                acc[(mh) * 4 + mi_][ni_] = __builtin_amdgcn_mfma_f32_16x16x32_fp8_fp8(          \
                    a_[mi_], b_[ni_], acc[(mh) * 4 + mi_][ni_], 0, 0, 0);                       \
        __builtin_amdgcn_s_setprio(0);                                                          \
    } while (0)

    // prologue: tile 0 -> slot 0
    STAGE(0, 0);

    const int nIter = K >> 7;   // pairs of BK=64 tiles
#pragma unroll 1
    for (int i = 0; i < nIter; ++i) {
        // ---- tile 2i from slot 0; stage tile 2i+1 -> slot 1 at phase 1 ----
        GPHASE(0, 0, 0, true,  STAGE(2 * i + 1, 1));
        GPHASE(0, 1, 0, false, ((void)0));
        GPHASE(0, 0, 1, false, ((void)0));
        GPHASE(0, 1, 1, false, ((void)0));
        // ---- tile 2i+1 from slot 1; stage tile 2i+2 -> slot 0 at phase 5 ----
        GPHASE(1, 0, 0, true,  do { if (i < nIter - 1) STAGE(2 * i + 2, 0); } while (0));
        GPHASE(1, 1, 0, false, ((void)0));
        GPHASE(1, 0, 1, false, ((void)0));
        GPHASE(1, 1, 1, false, ((void)0));
    }
#undef GPHASE
#undef STAGE

    // ---- epilogue: dequant scale, bias, bf16 round, f32 store ----
    const float ax = __uint_as_float(amax_bits[0]);
    const float aw = __uint_as_float(amax_bits[1]);
    const float sx = fminf(FP8_MAX_F / fmaxf(ax, 1e-12f), FP8_MAX_F);
    const float sw = fminf(FP8_MAX_F / fmaxf(aw, 1e-12f), FP8_MAX_F);
    const float s  = (1.0f / sx) * (1.0f / sw);

    const int lhi4 = lhi * 4;
#pragma unroll
    for (int ni = 0; ni < 4; ++ni) {
        const int col = colStart + wn64 + ni * 16 + l15;
        const float bv = bias[col];
#pragma unroll
        for (int mi = 0; mi < 8; ++mi) {
            const size_t rbase = (size_t)(rowStart + wm128 + mi * 16 + lhi4) * N + col;
#pragma unroll
            for (int j = 0; j < 4; ++j) {
                float t = acc[mi][ni][j] * s;   // mul...
                t = t + bv;                     // ...then add (match jnp op order)
                out[rbase + (size_t)j * N] = __bfloat162float(__float2bfloat16(t));
            }
        }
    }
}

extern "C" void kernel_launch(void* const* d_in, const int* in_sizes, int n_in,
                              void* d_out, int out_size, void* d_ws, size_t ws_size,
                              hipStream_t stream) {
    const float* input  = (const float*)d_in[0];
    const float* weight = (const float*)d_in[1];
    const float* bias   = (const float*)d_in[2];
    float* out = (float*)d_out;

    const int K = 1024;                       // weight [N,K] = [1024,1024]
    const int N = in_sizes[2];                // 1024 (bias length)
    const long nX = in_sizes[0];              // 33554432
    const long nW = (long)N * K;              // 1048576
    const int M = (int)(nX / K);              // 32768

    unsigned char* ws = (unsigned char*)d_ws;
    unsigned* amax = (unsigned*)ws;           // [0]=x amax bits, [1]=w amax bits
    unsigned char* Xq = ws + 256;
    unsigned char* Wq = ws + 256 + (size_t)M * K;

    hipMemsetAsync(d_ws, 0, 16, stream);

    amax2_kernel<<<2048, 256, 0, stream>>>(input, nX, weight, nW, amax + 0, amax + 1, 1984);
    quant2_kernel<<<2048, 256, 0, stream>>>(input, nX / 8, weight, nW / 8, amax,
                                            (unsigned*)Xq, (unsigned*)Wq, 1984);

    const int nbn = N / 256;
    const int nwg = (M / 256) * nbn;          // 512
    gemm_fp8_kernel<<<dim3(nwg), dim3(512), 0, stream>>>(Xq, Wq, bias, amax, out, M, N, K, nbn);
}

// Round 3
// 151.577 us; speedup vs baseline: 1.9324x; 1.5434x over previous
//
#include <hip/hip_runtime.h>
#include <hip/hip_bf16.h>

typedef float f32x4 __attribute__((ext_vector_type(4)));

#define FP8_MAX_F 448.0f

__device__ __forceinline__ float wave_max(float m) {
#pragma unroll
    for (int off = 32; off > 0; off >>= 1)
        m = fmaxf(m, __shfl_xor(m, off));
    return m;
}

// ---------------- stage 1: per-block abs-max partials (no atomics) ----------------
__global__ void amax2_kernel(const float* __restrict__ x, long nx,
                             const float* __restrict__ w, long nw,
                             float* __restrict__ px, float* __restrict__ pw,
                             int ga) {
    __shared__ float red[4];
    const float* src; long n; float* dst; int bid, blocks;
    if ((int)blockIdx.x < ga) { src = x; n = nx; dst = px; bid = blockIdx.x; blocks = ga; }
    else { src = w; n = nw; dst = pw; bid = blockIdx.x - ga; blocks = gridDim.x - ga; }

    const long stride = (long)blocks * blockDim.x * 16;
    long i = ((long)bid * blockDim.x + threadIdx.x) * 16;
    float m = 0.0f;
    for (; i < n; i += stride) {
        f32x4 v0 = *(const f32x4*)(src + i);
        f32x4 v1 = *(const f32x4*)(src + i + 4);
        f32x4 v2 = *(const f32x4*)(src + i + 8);
        f32x4 v3 = *(const f32x4*)(src + i + 12);
        float m0 = fmaxf(fmaxf(fabsf(v0.x), fabsf(v0.y)), fmaxf(fabsf(v0.z), fabsf(v0.w)));
        float m1 = fmaxf(fmaxf(fabsf(v1.x), fabsf(v1.y)), fmaxf(fabsf(v1.z), fabsf(v1.w)));
        float m2 = fmaxf(fmaxf(fabsf(v2.x), fabsf(v2.y)), fmaxf(fabsf(v2.z), fabsf(v2.w)));
        float m3 = fmaxf(fmaxf(fabsf(v3.x), fabsf(v3.y)), fmaxf(fabsf(v3.z), fabsf(v3.w)));
        m = fmaxf(m, fmaxf(fmaxf(m0, m1), fmaxf(m2, m3)));
    }
    m = wave_max(m);
    const int wave = threadIdx.x >> 6;
    if ((threadIdx.x & 63) == 0) red[wave] = m;
    __syncthreads();
    if (threadIdx.x == 0)
        dst[bid] = fmaxf(fmaxf(red[0], red[1]), fmaxf(red[2], red[3]));
}

// ---------------- stage 2: reduce partials -> amax bits (block 0 = x, block 1 = w) ----------------
__global__ void amax_final_kernel(const float* __restrict__ px, int npx,
                                  const float* __restrict__ pw, int npw,
                                  unsigned* __restrict__ amax) {
    __shared__ float red[4];
    const float* p; int n;
    if (blockIdx.x == 0) { p = px; n = npx; } else { p = pw; n = npw; }
    float m = 0.0f;
    for (int i = threadIdx.x; i < n; i += blockDim.x) m = fmaxf(m, p[i]);
    m = wave_max(m);
    const int wave = threadIdx.x >> 6;
    if ((threadIdx.x & 63) == 0) red[wave] = m;
    __syncthreads();
    if (threadIdx.x == 0) {
        m = fmaxf(fmaxf(red[0], red[1]), fmaxf(red[2], red[3]));
        amax[blockIdx.x] = __float_as_uint(m);
    }
}

// ---------------- fused quantize (8 floats/thread/iter -> uint2) ----------------
__global__ void quant2_kernel(const float* __restrict__ x, long nx8,
                              const float* __restrict__ w, long nw8,
                              const unsigned* __restrict__ amax_bits,
                              unsigned* __restrict__ qx, unsigned* __restrict__ qw,
                              int ga) {
    const float* src; long n8; unsigned* q; int bid, blocks; float a;
    if ((int)blockIdx.x < ga) { src = x; n8 = nx8; q = qx; bid = blockIdx.x; blocks = ga;
                                a = __uint_as_float(amax_bits[0]); }
    else { src = w; n8 = nw8; q = qw; bid = blockIdx.x - ga; blocks = gridDim.x - ga;
           a = __uint_as_float(amax_bits[1]); }
    const float scale = fminf(FP8_MAX_F / fmaxf(a, 1e-12f), FP8_MAX_F);

    const long stride = (long)blocks * blockDim.x;
    for (long i = (long)bid * blockDim.x + threadIdx.x; i < n8; i += stride) {
        f32x4 v0 = *(const f32x4*)(src + i * 8);
        f32x4 v1 = *(const f32x4*)(src + i * 8 + 4);
        float c0 = fminf(fmaxf(v0.x * scale, -FP8_MAX_F), FP8_MAX_F);
        float c1 = fminf(fmaxf(v0.y * scale, -FP8_MAX_F), FP8_MAX_F);
        float c2 = fminf(fmaxf(v0.z * scale, -FP8_MAX_F), FP8_MAX_F);
        float c3 = fminf(fmaxf(v0.w * scale, -FP8_MAX_F), FP8_MAX_F);
        float c4 = fminf(fmaxf(v1.x * scale, -FP8_MAX_F), FP8_MAX_F);
        float c5 = fminf(fmaxf(v1.y * scale, -FP8_MAX_F), FP8_MAX_F);
        float c6 = fminf(fmaxf(v1.z * scale, -FP8_MAX_F), FP8_MAX_F);
        float c7 = fminf(fmaxf(v1.w * scale, -FP8_MAX_F), FP8_MAX_F);
        int r0 = __builtin_amdgcn_cvt_pk_fp8_f32(c0, c1, 0, false);
        r0 = __builtin_amdgcn_cvt_pk_fp8_f32(c2, c3, r0, true);
        int r1 = __builtin_amdgcn_cvt_pk_fp8_f32(c4, c5, 0, false);
        r1 = __builtin_amdgcn_cvt_pk_fp8_f32(c6, c7, r1, true);
        uint2 rr; rr.x = (unsigned)r0; rr.y = (unsigned)r1;
        *(uint2*)(q + i * 2) = rr;
    }
}

// ---------------- fp8 GEMM, 256x256 tile, BK=64, 8-phase pipelined ----------------
// LDS layout per slot: [c = kbyte/16][256 rows][16B], row swizzled r' = r ^ ((c&3)<<1).
// Stage is linear (global_load_lds); the inverse swizzle is applied to the global src addr.
__global__ __launch_bounds__(512, 2) void gemm_fp8_kernel(
    const unsigned char* __restrict__ Xq,   // [M][K] fp8
    const unsigned char* __restrict__ Wq,   // [N][K] fp8
    const float* __restrict__ bias,         // [N]
    const unsigned* __restrict__ amax_bits, // [0]=x amax, [1]=w amax
    float* __restrict__ out,                // [M][N] f32 (bf16-rounded values)
    int M, int N, int K, int nbn)
{
    __shared__ unsigned char ldsA[2][16384];
    __shared__ unsigned char ldsB[2][16384];

    const int tid  = threadIdx.x;
    const int lane = tid & 63;
    const int wave = tid >> 6;
    const int wm128 = (wave >> 2) * 128;  // 2 M-halves
    const int wn64  = (wave & 3) * 64;    // 4 N-quarters

    const int l15 = lane & 15;
    const int lhi = lane >> 4;            // 0..3
    const int h   = lhi >> 1;             // 0..1 (chunk half within 32-K)
    const int lo8 = (lhi & 1) * 8;

    // XCD-aware swizzle (nwg % 8 == 0), bn-fastest for A-panel L2 reuse
    const int cpx = gridDim.x >> 3;
    const int wg  = ((int)blockIdx.x & 7) * cpx + ((int)blockIdx.x >> 3);
    const int bn = wg % nbn;
    const int bm = wg / nbn;
    const int rowStart = bm << 8;
    const int colStart = bn << 8;

    // per-ks read-addressing constants (c = ks*2 + h, swz = (c&3)<<1)
    const int cb0  = (0 * 2 + h) * 4096 + lo8;
    const int cb1  = (1 * 2 + h) * 4096 + lo8;
    const int lsw0 = l15 ^ (2 * h);
    const int lsw1 = l15 ^ (4 + 2 * h);

    // staging source offsets (inverse swizzle on global row)
    const int c0  = tid >> 8;       // 0/1
    const int rr_ = tid & 255;
    size_t aoffs0, aoffs1, boffs0, boffs1;
    {
        int ca = c0;           int ra = rr_ ^ ((ca & 3) << 1);
        int cb_ = 2 + c0;      int rb = rr_ ^ ((cb_ & 3) << 1);
        aoffs0 = (size_t)(rowStart + ra) * K + ca * 16;
        aoffs1 = (size_t)(rowStart + rb) * K + cb_ * 16;
        boffs0 = (size_t)(colStart + ra) * K + ca * 16;
        boffs1 = (size_t)(colStart + rb) * K + cb_ * 16;
    }
    const int tid16 = tid * 16;

    f32x4 acc[8][4] = {};

#define STAGE(t, slot)                                                                          \
    do {                                                                                        \
        const size_t kk_ = (size_t)(t) * 64;                                                    \
        __builtin_amdgcn_global_load_lds(                                                       \
            (const __attribute__((address_space(1))) void*)(Xq + aoffs0 + kk_),                 \
            (__attribute__((address_space(3))) void*)(&ldsA[slot][tid16]), 16, 0, 0);           \
        __builtin_amdgcn_global_load_lds(                                                       \
            (const __attribute__((address_space(1))) void*)(Xq + aoffs1 + kk_),                 \
            (__attribute__((address_space(3))) void*)(&ldsA[slot][8192 + tid16]), 16, 0, 0);    \
        __builtin_amdgcn_global_load_lds(                                                       \
            (const __attribute__((address_space(1))) void*)(Wq + boffs0 + kk_),                 \
            (__attribute__((address_space(3))) void*)(&ldsB[slot][tid16]), 16, 0, 0);           \
        __builtin_amdgcn_global_load_lds(                                                       \
            (const __attribute__((address_space(1))) void*)(Wq + boffs1 + kk_),                 \
            (__attribute__((address_space(3))) void*)(&ldsB[slot][8192 + tid16]), 16, 0, 0);    \
    } while (0)

#define GPHASE(slot, ks, mh, VMW, STG)                                                          \
    do {                                                                                        \
        if (VMW) asm volatile("s_waitcnt vmcnt(0)" ::: "memory");                               \
        __builtin_amdgcn_s_barrier();                                                           \
        __builtin_amdgcn_sched_barrier(0);                                                      \
        const unsigned char* pA_ = &ldsA[slot][cb##ks + ((wm128 + (mh)*64 + lsw##ks) << 4)];    \
        const unsigned char* pB_ = &ldsB[slot][cb##ks + ((wn64 + lsw##ks) << 4)];               \
        long a_[4], b_[4];                                                                      \
        _Pragma("unroll")                                                                       \
        for (int q_ = 0; q_ < 4; ++q_) {                                                        \
            a_[q_] = *(const long*)(pA_ + q_ * 256);                                            \
            b_[q_] = *(const long*)(pB_ + q_ * 256);                                            \
        }                                                                                       \
        STG;                                                                                    \
        __builtin_amdgcn_s_setprio(1);                                                          \
        _Pragma("unroll")                                                                       \
        for (int mi_ = 0; mi_ < 4; ++mi_)                                                       \
            _Pragma("unroll")                                                                   \
            for (int ni_ = 0; ni_ < 4; ++ni_)                                                   \
                acc[(mh) * 4 + mi_][ni_] = __builtin_amdgcn_mfma_f32_16x16x32_fp8_fp8(          \
                    a_[mi_], b_[ni_], acc[(mh) * 4 + mi_][ni_], 0, 0, 0);                       \
        __builtin_amdgcn_s_setprio(0);                                                          \
    } while (0)

    // prologue: tile 0 -> slot 0
    STAGE(0, 0);

    const int nIter = K >> 7;   // pairs of BK=64 tiles
#pragma unroll 1
    for (int i = 0; i < nIter; ++i) {
        // ---- tile 2i from slot 0; stage tile 2i+1 -> slot 1 at phase 1 ----
        GPHASE(0, 0, 0, true,  STAGE(2 * i + 1, 1));
        GPHASE(0, 1, 0, false, ((void)0));
        GPHASE(0, 0, 1, false, ((void)0));
        GPHASE(0, 1, 1, false, ((void)0));
        // ---- tile 2i+1 from slot 1; stage tile 2i+2 -> slot 0 at phase 5 ----
        GPHASE(1, 0, 0, true,  do { if (i < nIter - 1) STAGE(2 * i + 2, 0); } while (0));
        GPHASE(1, 1, 0, false, ((void)0));
        GPHASE(1, 0, 1, false, ((void)0));
        GPHASE(1, 1, 1, false, ((void)0));
    }
#undef GPHASE
#undef STAGE

    // ---- epilogue: dequant scale, bias, bf16 round, f32 store ----
    const float ax = __uint_as_float(amax_bits[0]);
    const float aw = __uint_as_float(amax_bits[1]);
    const float sx = fminf(FP8_MAX_F / fmaxf(ax, 1e-12f), FP8_MAX_F);
    const float sw = fminf(FP8_MAX_F / fmaxf(aw, 1e-12f), FP8_MAX_F);
    const float s  = (1.0f / sx) * (1.0f / sw);

    const int lhi4 = lhi * 4;
#pragma unroll
    for (int ni = 0; ni < 4; ++ni) {
        const int col = colStart + wn64 + ni * 16 + l15;
        const float bv = bias[col];
#pragma unroll
        for (int mi = 0; mi < 8; ++mi) {
            const size_t rbase = (size_t)(rowStart + wm128 + mi * 16 + lhi4) * N + col;
#pragma unroll
            for (int j = 0; j < 4; ++j) {
                float t = acc[mi][ni][j] * s;   // mul...
                t = t + bv;                     // ...then add (match jnp op order)
                out[rbase + (size_t)j * N] = __bfloat162float(__float2bfloat16(t));
            }
        }
    }
}

extern "C" void kernel_launch(void* const* d_in, const int* in_sizes, int n_in,
                              void* d_out, int out_size, void* d_ws, size_t ws_size,
                              hipStream_t stream) {
    const float* input  = (const float*)d_in[0];
    const float* weight = (const float*)d_in[1];
    const float* bias   = (const float*)d_in[2];
    float* out = (float*)d_out;

    const int K = 1024;                       // weight [N,K] = [1024,1024]
    const int N = in_sizes[2];                // 1024 (bias length)
    const long nX = in_sizes[0];              // 33554432
    const long nW = (long)N * K;              // 1048576
    const int M = (int)(nX / K);              // 32768

    const int GA = 1984;                      // input blocks (of 2048 total)
    const int GW = 64;                        // weight blocks

    unsigned char* ws = (unsigned char*)d_ws;
    unsigned* amax = (unsigned*)ws;           // [0]=x amax bits, [1]=w amax bits
    unsigned char* Xq = ws + 256;
    unsigned char* Wq = Xq + (size_t)M * K;
    float* px = (float*)(Wq + (size_t)N * K); // 1984 partials
    float* pw = px + GA;                      // 64 partials

    // stage 1: per-block partials (plain stores, no atomic contention)
    amax2_kernel<<<GA + GW, 256, 0, stream>>>(input, nX, weight, nW, px, pw, GA);
    // stage 2: 2 blocks reduce partials -> amax bits (deterministic, no memset needed)
    amax_final_kernel<<<2, 256, 0, stream>>>(px, GA, pw, GW, amax);

    quant2_kernel<<<2048, 256, 0, stream>>>(input, nX / 8, weight, nW / 8, amax,
                                            (unsigned*)Xq, (unsigned*)Wq, GA);

    const int nbn = N / 256;
    const int nwg = (M / 256) * nbn;          // 512
    gemm_fp8_kernel<<<dim3(nwg), dim3(512), 0, stream>>>(Xq, Wq, bias, amax, out, M, N, K, nbn);
}

// Round 4
// 142.802 us; speedup vs baseline: 2.0512x; 1.0615x over previous
//
#include <hip/hip_runtime.h>
#include <hip/hip_bf16.h>

typedef float f32x4 __attribute__((ext_vector_type(4)));
typedef long lx2 __attribute__((ext_vector_type(2)));

#define FP8_MAX_F 448.0f

__device__ __forceinline__ float wave_max(float m) {
#pragma unroll
    for (int off = 32; off > 0; off >>= 1)
        m = fmaxf(m, __shfl_xor(m, off));
    return m;
}

// ---------------- stage 1: per-block abs-max partials (no atomics) ----------------
__global__ void amax2_kernel(const float* __restrict__ x, long nx,
                             const float* __restrict__ w, long nw,
                             float* __restrict__ px, float* __restrict__ pw,
                             int ga) {
    __shared__ float red[4];
    const float* src; long n; float* dst; int bid, blocks;
    if ((int)blockIdx.x < ga) { src = x; n = nx; dst = px; bid = blockIdx.x; blocks = ga; }
    else { src = w; n = nw; dst = pw; bid = blockIdx.x - ga; blocks = gridDim.x - ga; }

    const long stride = (long)blocks * blockDim.x * 16;
    long i = ((long)bid * blockDim.x + threadIdx.x) * 16;
    float m = 0.0f;
    for (; i < n; i += stride) {
        f32x4 v0 = *(const f32x4*)(src + i);
        f32x4 v1 = *(const f32x4*)(src + i + 4);
        f32x4 v2 = *(const f32x4*)(src + i + 8);
        f32x4 v3 = *(const f32x4*)(src + i + 12);
        float m0 = fmaxf(fmaxf(fabsf(v0.x), fabsf(v0.y)), fmaxf(fabsf(v0.z), fabsf(v0.w)));
        float m1 = fmaxf(fmaxf(fabsf(v1.x), fabsf(v1.y)), fmaxf(fabsf(v1.z), fabsf(v1.w)));
        float m2 = fmaxf(fmaxf(fabsf(v2.x), fabsf(v2.y)), fmaxf(fabsf(v2.z), fabsf(v2.w)));
        float m3 = fmaxf(fmaxf(fabsf(v3.x), fabsf(v3.y)), fmaxf(fabsf(v3.z), fabsf(v3.w)));
        m = fmaxf(m, fmaxf(fmaxf(m0, m1), fmaxf(m2, m3)));
    }
    m = wave_max(m);
    const int wave = threadIdx.x >> 6;
    if ((threadIdx.x & 63) == 0) red[wave] = m;
    __syncthreads();
    if (threadIdx.x == 0)
        dst[bid] = fmaxf(fmaxf(red[0], red[1]), fmaxf(red[2], red[3]));
}

// ---------------- stage 2: reduce partials -> amax bits (block 0 = x, block 1 = w) ----------------
__global__ void amax_final_kernel(const float* __restrict__ px, int npx,
                                  const float* __restrict__ pw, int npw,
                                  unsigned* __restrict__ amax) {
    __shared__ float red[4];
    const float* p; int n;
    if (blockIdx.x == 0) { p = px; n = npx; } else { p = pw; n = npw; }
    float m = 0.0f;
    for (int i = threadIdx.x; i < n; i += blockDim.x) m = fmaxf(m, p[i]);
    m = wave_max(m);
    const int wave = threadIdx.x >> 6;
    if ((threadIdx.x & 63) == 0) red[wave] = m;
    __syncthreads();
    if (threadIdx.x == 0) {
        m = fmaxf(fmaxf(red[0], red[1]), fmaxf(red[2], red[3]));
        amax[blockIdx.x] = __float_as_uint(m);
    }
}

// ---------------- fused quantize (8 floats/thread/iter -> uint2) ----------------
__global__ void quant2_kernel(const float* __restrict__ x, long nx8,
                              const float* __restrict__ w, long nw8,
                              const unsigned* __restrict__ amax_bits,
                              unsigned* __restrict__ qx, unsigned* __restrict__ qw,
                              int ga) {
    const float* src; long n8; unsigned* q; int bid, blocks; float a;
    if ((int)blockIdx.x < ga) { src = x; n8 = nx8; q = qx; bid = blockIdx.x; blocks = ga;
                                a = __uint_as_float(amax_bits[0]); }
    else { src = w; n8 = nw8; q = qw; bid = blockIdx.x - ga; blocks = gridDim.x - ga;
           a = __uint_as_float(amax_bits[1]); }
    const float scale = fminf(FP8_MAX_F / fmaxf(a, 1e-12f), FP8_MAX_F);

    const long stride = (long)blocks * blockDim.x;
    for (long i = (long)bid * blockDim.x + threadIdx.x; i < n8; i += stride) {
        f32x4 v0 = *(const f32x4*)(src + i * 8);
        f32x4 v1 = *(const f32x4*)(src + i * 8 + 4);
        float c0 = fminf(fmaxf(v0.x * scale, -FP8_MAX_F), FP8_MAX_F);
        float c1 = fminf(fmaxf(v0.y * scale, -FP8_MAX_F), FP8_MAX_F);
        float c2 = fminf(fmaxf(v0.z * scale, -FP8_MAX_F), FP8_MAX_F);
        float c3 = fminf(fmaxf(v0.w * scale, -FP8_MAX_F), FP8_MAX_F);
        float c4 = fminf(fmaxf(v1.x * scale, -FP8_MAX_F), FP8_MAX_F);
        float c5 = fminf(fmaxf(v1.y * scale, -FP8_MAX_F), FP8_MAX_F);
        float c6 = fminf(fmaxf(v1.z * scale, -FP8_MAX_F), FP8_MAX_F);
        float c7 = fminf(fmaxf(v1.w * scale, -FP8_MAX_F), FP8_MAX_F);
        int r0 = __builtin_amdgcn_cvt_pk_fp8_f32(c0, c1, 0, false);
        r0 = __builtin_amdgcn_cvt_pk_fp8_f32(c2, c3, r0, true);
        int r1 = __builtin_amdgcn_cvt_pk_fp8_f32(c4, c5, 0, false);
        r1 = __builtin_amdgcn_cvt_pk_fp8_f32(c6, c7, r1, true);
        uint2 rr; rr.x = (unsigned)r0; rr.y = (unsigned)r1;
        *(uint2*)(q + i * 2) = rr;
    }
}

// ---------------- fp8 GEMM, 256x256 tile, BK=64, b128-fragment pipelined ----------------
// LDS per slot, per side: linear [c=0..3][row=0..255][16B] (unit u = c*256+row at byte 16u).
// Lane (l15,lhi) ds_read_b128's unit (row, c=lhi): bytes 0..7 feed MFMA k-step 0,
// bytes 8..15 feed k-step 1 (k->slot mapping is free; A/B use the same mapping).
// Per quarter-wave: 16 lanes x 4 dwords tile all 32 banks exactly 2x -> conflict-free.
__global__ __launch_bounds__(512, 2) void gemm_fp8_kernel(
    const unsigned char* __restrict__ Xq,   // [M][K] fp8
    const unsigned char* __restrict__ Wq,   // [N][K] fp8
    const float* __restrict__ bias,         // [N]
    const unsigned* __restrict__ amax_bits, // [0]=x amax, [1]=w amax
    float* __restrict__ out,                // [M][N] f32 (bf16-rounded values)
    int M, int N, int K, int nbn)
{
    __shared__ unsigned char ldsA[2][16384];
    __shared__ unsigned char ldsB[2][16384];

    const int tid  = threadIdx.x;
    const int lane = tid & 63;
    const int wave = tid >> 6;
    const int wm128 = (wave >> 2) * 128;  // 2 M-halves
    const int wn64  = (wave & 3) * 64;    // 4 N-quarters

    const int l15 = lane & 15;
    const int lhi = lane >> 4;            // 0..3 -> which 16B k-chunk

    // XCD-aware swizzle (nwg % 8 == 0), bn-fastest for A-panel L2 reuse
    const int cpx = gridDim.x >> 3;
    const int wg  = ((int)blockIdx.x & 7) * cpx + ((int)blockIdx.x >> 3);
    const int bn = wg % nbn;
    const int bm = wg / nbn;
    const int rowStart = bm << 8;
    const int colStart = bn << 8;

    // read offsets (linear layout)
    const int aoff0 = lhi * 4096 + (wm128 + l15) * 16;   // mh=0; mh=1 at +1024
    const int boff  = lhi * 4096 + (wn64 + l15) * 16;

    // staging source offsets (fully linear, no swizzle)
    const int c0  = tid >> 8;       // 0/1
    const int rr_ = tid & 255;
    const size_t aoffs = (size_t)(rowStart + rr_) * K + c0 * 16;
    const size_t boffs = (size_t)(colStart + rr_) * K + c0 * 16;
    const int tid16 = tid * 16;

    f32x4 acc[8][4] = {};

#define STAGE(t, slot)                                                                          \
    do {                                                                                        \
        const size_t kk_ = (size_t)(t) * 64;                                                    \
        __builtin_amdgcn_global_load_lds(                                                       \
            (const __attribute__((address_space(1))) void*)(Xq + aoffs + kk_),                  \
            (__attribute__((address_space(3))) void*)(&ldsA[slot][tid16]), 16, 0, 0);           \
        __builtin_amdgcn_global_load_lds(                                                       \
            (const __attribute__((address_space(1))) void*)(Xq + aoffs + 32 + kk_),             \
            (__attribute__((address_space(3))) void*)(&ldsA[slot][8192 + tid16]), 16, 0, 0);    \
        __builtin_amdgcn_global_load_lds(                                                       \
            (const __attribute__((address_space(1))) void*)(Wq + boffs + kk_),                  \
            (__attribute__((address_space(3))) void*)(&ldsB[slot][tid16]), 16, 0, 0);           \
        __builtin_amdgcn_global_load_lds(                                                       \
            (const __attribute__((address_space(1))) void*)(Wq + boffs + 32 + kk_),             \
            (__attribute__((address_space(3))) void*)(&ldsB[slot][8192 + tid16]), 16, 0, 0);    \
    } while (0)

// One 64-K tile: phase1 (vmcnt, bar, read B + A-mh0, stage, 32 MFMA),
//                phase2 (bar, read A-mh1, 32 MFMA). B regs reused across phases.
#define TILE(slot, STG)                                                                         \
    do {                                                                                        \
        asm volatile("s_waitcnt vmcnt(0)" ::: "memory");                                        \
        __builtin_amdgcn_s_barrier();                                                           \
        __builtin_amdgcn_sched_barrier(0);                                                      \
        lx2 af[4], bf[4];                                                                       \
        _Pragma("unroll")                                                                       \
        for (int q_ = 0; q_ < 4; ++q_) {                                                        \
            bf[q_] = *(const lx2*)(&ldsB[slot][boff + q_ * 256]);                               \
            af[q_] = *(const lx2*)(&ldsA[slot][aoff0 + q_ * 256]);                              \
        }                                                                                       \
        STG;                                                                                    \
        asm volatile("s_waitcnt lgkmcnt(0)" ::: "memory");                                      \
        __builtin_amdgcn_sched_barrier(0);                                                      \
        __builtin_amdgcn_s_setprio(1);                                                          \
        _Pragma("unroll")                                                                       \
        for (int ks_ = 0; ks_ < 2; ++ks_)                                                       \
            _Pragma("unroll")                                                                   \
            for (int mi_ = 0; mi_ < 4; ++mi_)                                                   \
                _Pragma("unroll")                                                               \
                for (int ni_ = 0; ni_ < 4; ++ni_)                                               \
                    acc[mi_][ni_] = __builtin_amdgcn_mfma_f32_16x16x32_fp8_fp8(                 \
                        af[mi_][ks_], bf[ni_][ks_], acc[mi_][ni_], 0, 0, 0);                    \
        __builtin_amdgcn_s_setprio(0);                                                          \
        __builtin_amdgcn_s_barrier();                                                           \
        __builtin_amdgcn_sched_barrier(0);                                                      \
        _Pragma("unroll")                                                                       \
        for (int q_ = 0; q_ < 4; ++q_)                                                          \
            af[q_] = *(const lx2*)(&ldsA[slot][aoff0 + 1024 + q_ * 256]);                       \
        asm volatile("s_waitcnt lgkmcnt(0)" ::: "memory");                                      \
        __builtin_amdgcn_sched_barrier(0);                                                      \
        __builtin_amdgcn_s_setprio(1);                                                          \
        _Pragma("unroll")                                                                       \
        for (int ks_ = 0; ks_ < 2; ++ks_)                                                       \
            _Pragma("unroll")                                                                   \
            for (int mi_ = 0; mi_ < 4; ++mi_)                                                   \
                _Pragma("unroll")                                                               \
                for (int ni_ = 0; ni_ < 4; ++ni_)                                               \
                    acc[4 + mi_][ni_] = __builtin_amdgcn_mfma_f32_16x16x32_fp8_fp8(             \
                        af[mi_][ks_], bf[ni_][ks_], acc[4 + mi_][ni_], 0, 0, 0);                \
        __builtin_amdgcn_s_setprio(0);                                                          \
    } while (0)

    // prologue: tile 0 -> slot 0
    STAGE(0, 0);

    const int nIter = K >> 7;   // pairs of BK=64 tiles (= 8 for K=1024)
#pragma unroll 1
    for (int i = 0; i < nIter; ++i) {
        TILE(0, STAGE(2 * i + 1, 1));
        TILE(1, do { if (i < nIter - 1) STAGE(2 * i + 2, 0); } while (0));
    }
#undef TILE
#undef STAGE

    // ---- epilogue: dequant scale, bias, bf16 round, f32 store ----
    const float ax = __uint_as_float(amax_bits[0]);
    const float aw = __uint_as_float(amax_bits[1]);
    const float sx = fminf(FP8_MAX_F / fmaxf(ax, 1e-12f), FP8_MAX_F);
    const float sw = fminf(FP8_MAX_F / fmaxf(aw, 1e-12f), FP8_MAX_F);
    const float s  = (1.0f / sx) * (1.0f / sw);

    const int lhi4 = (lane >> 4) * 4;
#pragma unroll
    for (int ni = 0; ni < 4; ++ni) {
        const int col = colStart + wn64 + ni * 16 + l15;
        const float bv = bias[col];
#pragma unroll
        for (int mi = 0; mi < 8; ++mi) {
            const size_t rbase = (size_t)(rowStart + wm128 + mi * 16 + lhi4) * N + col;
#pragma unroll
            for (int j = 0; j < 4; ++j) {
                float t = acc[mi][ni][j] * s;   // mul...
                t = t + bv;                     // ...then add (match jnp op order)
                out[rbase + (size_t)j * N] = __bfloat162float(__float2bfloat16(t));
            }
        }
    }
}

extern "C" void kernel_launch(void* const* d_in, const int* in_sizes, int n_in,
                              void* d_out, int out_size, void* d_ws, size_t ws_size,
                              hipStream_t stream) {
    const float* input  = (const float*)d_in[0];
    const float* weight = (const float*)d_in[1];
    const float* bias   = (const float*)d_in[2];
    float* out = (float*)d_out;

    const int K = 1024;                       // weight [N,K] = [1024,1024]
    const int N = in_sizes[2];                // 1024 (bias length)
    const long nX = in_sizes[0];              // 33554432
    const long nW = (long)N * K;              // 1048576
    const int M = (int)(nX / K);              // 32768

    const int GA = 1984;                      // input blocks (of 2048 total)
    const int GW = 64;                        // weight blocks

    unsigned char* ws = (unsigned char*)d_ws;
    unsigned* amax = (unsigned*)ws;           // [0]=x amax bits, [1]=w amax bits
    unsigned char* Xq = ws + 256;
    unsigned char* Wq = Xq + (size_t)M * K;
    float* px = (float*)(Wq + (size_t)N * K); // 1984 partials
    float* pw = px + GA;                      // 64 partials

    // stage 1: per-block partials (plain stores, no atomic contention)
    amax2_kernel<<<GA + GW, 256, 0, stream>>>(input, nX, weight, nW, px, pw, GA);
    // stage 2: 2 blocks reduce partials -> amax bits (deterministic, no memset needed)
    amax_final_kernel<<<2, 256, 0, stream>>>(px, GA, pw, GW, amax);

    quant2_kernel<<<2048, 256, 0, stream>>>(input, nX / 8, weight, nW / 8, amax,
                                            (unsigned*)Xq, (unsigned*)Wq, GA);

    const int nbn = N / 256;
    const int nwg = (M / 256) * nbn;          // 512
    gemm_fp8_kernel<<<dim3(nwg), dim3(512), 0, stream>>>(Xq, Wq, bias, amax, out, M, N, K, nbn);
}